// Round 1
// baseline (2709.184 us; speedup 1.0000x reference)
//
#include <hip/hip_runtime.h>
#include <hip/hip_bf16.h>
#include <math.h>

// Problem constants
// x: [512,1,28,28]  z: [512,64]
// fc: 64 -> 2048 ; reshape [512,128,4,4]
// convT0: 128->64, 4x4 -> 7x7   (s2,p1,op0)
// convT1: 64->32, 7x7 -> 14x14  (s2,p1,op1)
// convT2: 32->32, 14x14 -> 28x28(s2,p1,op1)
// conv:   32->1, 28x28 (k3,p1)  -> logits [512,784]
// C[i,j] = sp[j] - dot(X[i], L[j])   (512x512, K=784)
// SAG scan 1000 iters ; P[i,:] = softmax(beta - C[i,:]) / 512
// kl = sum P log P + 2 log 512

__global__ void fc_relu_k(const float* __restrict__ z, const float* __restrict__ w,
                          const float* __restrict__ b, float* __restrict__ out) {
  int idx = blockIdx.x * 256 + threadIdx.x;   // 512*2048
  int n = idx >> 11, c = idx & 2047;
  const float* zr = z + n * 64;
  float acc = b[c];
#pragma unroll
  for (int k = 0; k < 64; ++k) acc = fmaf(zr[k], w[k * 2048 + c], acc);
  out[idx] = fmaxf(acc, 0.f);
}

template <int CIN, int COUT, int HIN, int HOUT>
__global__ void convt_relu_k(const float* __restrict__ x, const float* __restrict__ w,
                             const float* __restrict__ bias, float* __restrict__ y) {
  int idx = blockIdx.x * 256 + threadIdx.x;   // NS*COUT*HOUT*HOUT, exact grid
  int ow = idx % HOUT;
  int oh = (idx / HOUT) % HOUT;
  int co = (idx / (HOUT * HOUT)) % COUT;
  int n = idx / (HOUT * HOUT * COUT);
  float acc = bias[co];
#pragma unroll
  for (int kh = 0; kh < 3; ++kh) {
    int th = oh + 1 - kh;
    if (th < 0 || (th & 1)) continue;
    int ih = th >> 1;
    if (ih >= HIN) continue;
#pragma unroll
    for (int kw = 0; kw < 3; ++kw) {
      int tw = ow + 1 - kw;
      if (tw < 0 || (tw & 1)) continue;
      int iw = tw >> 1;
      if (iw >= HIN) continue;
      const float* xp = x + (n * CIN * HIN + ih) * HIN + iw;   // + ci*HIN*HIN
      const float* wp = w + co * 9 + kh * 3 + kw;              // + ci*COUT*9
      for (int ci = 0; ci < CIN; ++ci)
        acc = fmaf(xp[ci * HIN * HIN], wp[ci * COUT * 9], acc);
    }
  }
  y[idx] = fmaxf(acc, 0.f);
}

__global__ void conv_final_k(const float* __restrict__ x, const float* __restrict__ w,
                             const float* __restrict__ bias, float* __restrict__ y) {
  int idx = blockIdx.x * 256 + threadIdx.x;   // 512*784
  int ow = idx % 28, oh = (idx / 28) % 28, n = idx / 784;
  float acc = bias[0];
  for (int ci = 0; ci < 32; ++ci) {
#pragma unroll
    for (int kh = 0; kh < 3; ++kh) {
      int ih = oh - 1 + kh;
      if (ih < 0 || ih >= 28) continue;
#pragma unroll
      for (int kw = 0; kw < 3; ++kw) {
        int iw = ow - 1 + kw;
        if (iw < 0 || iw >= 28) continue;
        acc = fmaf(x[((n * 32 + ci) * 28 + ih) * 28 + iw], w[ci * 9 + kh * 3 + kw], acc);
      }
    }
  }
  y[idx] = acc;
}

__global__ void softplus_k(const float* __restrict__ L, float* __restrict__ sp) {
  __shared__ float red[256];
  int j = blockIdx.x, tid = threadIdx.x;
  float s = 0.f;
  for (int p = tid; p < 784; p += 256) {
    float v = L[j * 784 + p];
    s += fmaxf(v, 0.f) + log1pf(__expf(-fabsf(v)));
  }
  red[tid] = s;
  __syncthreads();
  for (int st = 128; st > 0; st >>= 1) {
    if (tid < st) red[tid] += red[tid + st];
    __syncthreads();
  }
  if (tid == 0) sp[j] = red[0];
}

__global__ void cost_k(const float* __restrict__ X, const float* __restrict__ L,
                       const float* __restrict__ sp, float* __restrict__ C) {
  __shared__ float Xs[16][17], Ls[16][17];
  int tx = threadIdx.x, ty = threadIdx.y;
  int i = blockIdx.y * 16 + ty, j0 = blockIdx.x * 16;
  float acc = 0.f;
  for (int k0 = 0; k0 < 784; k0 += 16) {
    Xs[ty][tx] = X[i * 784 + k0 + tx];
    Ls[ty][tx] = L[(j0 + ty) * 784 + k0 + tx];
    __syncthreads();
#pragma unroll
    for (int kk = 0; kk < 16; ++kk) acc = fmaf(Xs[ty][kk], Ls[tx][kk], acc);
    __syncthreads();
  }
  C[i * 512 + j0 + tx] = sp[j0 + tx] - acc;
}

__global__ void sag_k(const float* __restrict__ C, const int* __restrict__ idx,
                      float* __restrict__ stored, float* __restrict__ beta_out) {
  int lane = threadIdx.x;
  float beta[8], ssum[8];
#pragma unroll
  for (int r = 0; r < 8; ++r) { beta[r] = 0.f; ssum[r] = 0.f; }
  const float invn = 1.0f / 512.0f;
  for (int t = 0; t < 1000; ++t) {
    int i = idx[t];
    const float* Crow = C + i * 512;
    float s[8];
    float m = -1e30f;
#pragma unroll
    for (int r = 0; r < 8; ++r) {
      s[r] = beta[r] - Crow[lane + 64 * r];
      m = fmaxf(m, s[r]);
    }
#pragma unroll
    for (int off = 32; off >= 1; off >>= 1) m = fmaxf(m, __shfl_xor(m, off, 64));
    float e[8], S = 0.f;
#pragma unroll
    for (int r = 0; r < 8; ++r) {
      e[r] = __expf(s[r] - m);
      S += e[r];
    }
#pragma unroll
    for (int off = 32; off >= 1; off >>= 1) S += __shfl_xor(S, off, 64);
    float invS = 1.0f / S;
    float* srow = stored + i * 512;
#pragma unroll
    for (int r = 0; r < 8; ++r) {
      float g = invn * (invn - e[r] * invS);
      float old = srow[lane + 64 * r];
      ssum[r] += g - old;
      srow[lane + 64 * r] = g;
      beta[r] += ssum[r];   // lr/n_src = reg = 1
    }
  }
#pragma unroll
  for (int r = 0; r < 8; ++r) beta_out[lane + 64 * r] = beta[r];
}

__global__ void p_k(const float* __restrict__ C, const float* __restrict__ beta,
                    float* __restrict__ P, float* __restrict__ rowsum) {
  __shared__ float red[256];
  int i = blockIdx.x, tid = threadIdx.x;
  float u0 = beta[tid] - C[i * 512 + tid];
  float u1 = beta[tid + 256] - C[i * 512 + tid + 256];
  float m = fmaxf(u0, u1);
  red[tid] = m;
  __syncthreads();
  for (int st = 128; st > 0; st >>= 1) {
    if (tid < st) red[tid] = fmaxf(red[tid], red[tid + st]);
    __syncthreads();
  }
  m = red[0];
  __syncthreads();
  float e0 = __expf(u0 - m), e1 = __expf(u1 - m);
  red[tid] = e0 + e1;
  __syncthreads();
  for (int st = 128; st > 0; st >>= 1) {
    if (tid < st) red[tid] += red[tid + st];
    __syncthreads();
  }
  float lse = m + logf(red[0]);
  __syncthreads();
  const float log512 = 6.238324625039508f;
  float p0 = __expf(u0 - lse) * (1.0f / 512.0f);
  float p1 = __expf(u1 - lse) * (1.0f / 512.0f);
  P[i * 512 + tid] = p0;
  P[i * 512 + tid + 256] = p1;
  float pl = p0 * (u0 - lse - log512) + p1 * (u1 - lse - log512);
  red[tid] = pl;
  __syncthreads();
  for (int st = 128; st > 0; st >>= 1) {
    if (tid < st) red[tid] += red[tid + st];
    __syncthreads();
  }
  if (tid == 0) rowsum[i] = red[0];
}

__global__ void kl_k(const float* __restrict__ rowsum, float* __restrict__ out_kl) {
  __shared__ float red[512];
  int tid = threadIdx.x;
  red[tid] = rowsum[tid];
  __syncthreads();
  for (int st = 256; st > 0; st >>= 1) {
    if (tid < st) red[tid] += red[tid + st];
    __syncthreads();
  }
  if (tid == 0) out_kl[0] = red[0] + 2.0f * 6.238324625039508f;
}

extern "C" void kernel_launch(void* const* d_in, const int* in_sizes, int n_in,
                              void* d_out, int out_size, void* d_ws, size_t ws_size,
                              hipStream_t stream) {
  const float* x = (const float*)d_in[0];
  const float* z = (const float*)d_in[1];
  const float* fc_w = (const float*)d_in[2];
  const float* fc_b = (const float*)d_in[3];
  const float* ct0_w = (const float*)d_in[4];
  const float* ct0_b = (const float*)d_in[5];
  const float* ct1_w = (const float*)d_in[6];
  const float* ct1_b = (const float*)d_in[7];
  const float* fct_w = (const float*)d_in[8];
  const float* fct_b = (const float*)d_in[9];
  const float* conv_w = (const float*)d_in[10];
  const float* conv_b = (const float*)d_in[11];
  const int* idx = (const int*)d_in[12];

  float* out = (float*)d_out;
  float* Pout = out;               // 512*512
  float* Cout = out + 262144;      // 512*512
  float* klout = out + 524288;     // 1

  float* ws = (float*)d_ws;
  float* h0 = ws;                       // 512*2048       = 1048576
  float* h1 = h0 + 1048576;             // 512*64*49      = 1605632
  float* h2 = h1 + 1605632;             // 512*32*196     = 3211264
  float* h3 = h2 + 3211264;             // 512*32*784     = 12845056
  float* logit = h3 + 12845056;         // 512*784        = 401408
  float* sp = logit + 401408;           // 512
  float* beta = sp + 512;               // 512
  float* stored = beta + 512;           // 512*512        = 262144
  float* rowsum = stored + 262144;      // 512

  hipMemsetAsync(stored, 0, 262144 * sizeof(float), stream);

  fc_relu_k<<<4096, 256, 0, stream>>>(z, fc_w, fc_b, h0);
  convt_relu_k<128, 64, 4, 7><<<6272, 256, 0, stream>>>(h0, ct0_w, ct0_b, h1);
  convt_relu_k<64, 32, 7, 14><<<12544, 256, 0, stream>>>(h1, ct1_w, ct1_b, h2);
  convt_relu_k<32, 32, 14, 28><<<50176, 256, 0, stream>>>(h2, fct_w, fct_b, h3);
  conv_final_k<<<1568, 256, 0, stream>>>(h3, conv_w, conv_b, logit);
  softplus_k<<<512, 256, 0, stream>>>(logit, sp);
  dim3 bt(16, 16);
  cost_k<<<dim3(32, 32), bt, 0, stream>>>(x, logit, sp, Cout);
  sag_k<<<1, 64, 0, stream>>>(Cout, idx, stored, beta);
  p_k<<<512, 256, 0, stream>>>(Cout, beta, Pout, rowsum);
  kl_k<<<1, 512, 0, stream>>>(rowsum, klout);
}

// Round 2
// 907.497 us; speedup vs baseline: 2.9853x; 2.9853x over previous
//
#include <hip/hip_runtime.h>
#include <hip/hip_bf16.h>
#include <math.h>

// x: [512,1,28,28]  z: [512,64]
// fc: 64 -> 2048 ; reshape [512,128,4,4]
// convT0: 128->64, 4x4 -> 7x7   (s2,p1,op0)
// convT1: 64->32, 7x7 -> 14x14  (s2,p1,op1)
// convT2: 32->32, 14x14 -> 28x28(s2,p1,op1)
// conv:   32->1, 28x28 (k3,p1)  -> logits [512,784]
// C[i,j] = sp[j] - dot(X[i], L[j])   (512x512, K=784)
// SAG scan 1000 iters ; P[i,:] = softmax(beta - C[i,:]) / 512
// kl = sum P log P + 2 log 512

// ---------------- FC ----------------
__global__ void fc_relu_k(const float* __restrict__ z, const float* __restrict__ w,
                          const float* __restrict__ b, float* __restrict__ out) {
  int n = blockIdx.x >> 1;                               // 2 blocks per image
  int c0 = ((blockIdx.x & 1) << 10) + threadIdx.x * 4;   // 4 outputs/thread
  const float* zr = z + n * 64;                          // uniform per block -> s_loads
  float4 acc = *(const float4*)&b[c0];
#pragma unroll
  for (int k = 0; k < 64; ++k) {
    float zk = zr[k];
    float4 wv = *(const float4*)&w[k * 2048 + c0];
    acc.x = fmaf(zk, wv.x, acc.x);
    acc.y = fmaf(zk, wv.y, acc.y);
    acc.z = fmaf(zk, wv.z, acc.z);
    acc.w = fmaf(zk, wv.w, acc.w);
  }
  acc.x = fmaxf(acc.x, 0.f); acc.y = fmaxf(acc.y, 0.f);
  acc.z = fmaxf(acc.z, 0.f); acc.w = fmaxf(acc.w, 0.f);
  *(float4*)&out[n * 2048 + c0] = acc;
}

// ---------------- ConvT (quad-gather) ----------------
// out(2a,2b)     = x[a][b]*w[1][1]
// out(2a,2b+1)   = x[a][b+1]*w[1][0] + x[a][b]*w[1][2]
// out(2a+1,2b)   = x[a+1][b]*w[0][1] + x[a][b]*w[2][1]
// out(2a+1,2b+1) = x[a+1][b+1]*w[0][0] + x[a+1][b]*w[0][2] + x[a][b+1]*w[2][0] + x[a][b]*w[2][2]
#define TAPF(T, P, XV) { \
  const float4* w4_ = reinterpret_cast<const float4*>(&wt[((T) * CIN + ci) * 8]); \
  float4 wa_ = w4_[0], wb_ = w4_[1]; \
  acc[P][0] = fmaf(XV, wa_.x, acc[P][0]); \
  acc[P][1] = fmaf(XV, wa_.y, acc[P][1]); \
  acc[P][2] = fmaf(XV, wa_.z, acc[P][2]); \
  acc[P][3] = fmaf(XV, wa_.w, acc[P][3]); \
  acc[P][4] = fmaf(XV, wb_.x, acc[P][4]); \
  acc[P][5] = fmaf(XV, wb_.y, acc[P][5]); \
  acc[P][6] = fmaf(XV, wb_.z, acc[P][6]); \
  acc[P][7] = fmaf(XV, wb_.w, acc[P][7]); }

template <int CIN, int COUT, int HIN, int HOUT>
__global__ void convt_quad_k(const float* __restrict__ x, const float* __restrict__ w,
                             const float* __restrict__ bias, float* __restrict__ y) {
  constexpr bool FULL = (HOUT == 2 * HIN);
  constexpr int QP = HIN * HIN;
  __shared__ float wt[9 * CIN * 8];   // [tap][ci][co8]
  const int tid = threadIdx.x;
  const int g8 = blockIdx.y * 8;
  // stage co-slice of weights: w[ci][co][kh][kw] -> wt[(t*CIN+ci)*8+cl]
  for (int e = tid; e < 9 * CIN * 8; e += 256) {
    int cl = e & 7;
    int rest = e >> 3;
    int ci = rest & (CIN - 1);
    int t = rest / CIN;
    wt[e] = w[((size_t)ci * COUT + g8 + cl) * 9 + t];
  }
  __syncthreads();

  int q = blockIdx.x * 256 + tid;
  int n = q / QP;
  int pq = q % QP;
  int a = pq / HIN, b = pq % HIN;
  const bool oka = (a + 1 < HIN), okb = (b + 1 < HIN);
  const float* xim = x + (size_t)n * CIN * QP + a * HIN + b;

  float acc[4][8];
#pragma unroll
  for (int p = 0; p < 4; ++p)
#pragma unroll
    for (int c = 0; c < 8; ++c) acc[p][c] = 0.f;

  for (int ci = 0; ci < CIN; ++ci) {
    const float* xc = xim + ci * QP;
    float x00 = xc[0];
    float x01 = okb ? xc[1] : 0.f;
    float x10 = oka ? xc[HIN] : 0.f;
    float x11 = (oka && okb) ? xc[HIN + 1] : 0.f;
    TAPF(4, 0, x00)
    TAPF(3, 1, x01) TAPF(5, 1, x00)
    TAPF(1, 2, x10) TAPF(7, 2, x00)
    TAPF(0, 3, x11) TAPF(2, 3, x10) TAPF(6, 3, x01) TAPF(8, 3, x00)
  }

  int oh0 = 2 * a, ow0 = 2 * b;
  bool vh = FULL || (oh0 + 1 < HOUT);
  bool vw = FULL || (ow0 + 1 < HOUT);
#pragma unroll
  for (int c = 0; c < 8; ++c) {
    float bv = bias[g8 + c];
    float o00 = fmaxf(acc[0][c] + bv, 0.f);
    float o01 = fmaxf(acc[1][c] + bv, 0.f);
    float o10 = fmaxf(acc[2][c] + bv, 0.f);
    float o11 = fmaxf(acc[3][c] + bv, 0.f);
    float* yb = y + (((size_t)n * COUT + g8 + c) * HOUT + oh0) * (size_t)HOUT + ow0;
    if (FULL) {
      *(float2*)yb = make_float2(o00, o01);
      *(float2*)(yb + HOUT) = make_float2(o10, o11);
    } else {
      yb[0] = o00;
      if (vw) yb[1] = o01;
      if (vh) yb[HOUT] = o10;
      if (vh && vw) yb[HOUT + 1] = o11;
    }
  }
}

// ---------------- final 32->1 conv ----------------
__global__ void conv_final_k(const float* __restrict__ x, const float* __restrict__ w,
                             const float* __restrict__ bias, float* __restrict__ y) {
  __shared__ float ws_[288];
  int tid = threadIdx.x;
  ws_[tid] = w[tid & 255];   // placeholder fill; fixed below
  if (tid < 288 - 256) ws_[256 + tid] = w[256 + tid];
  if (tid < 256) ws_[tid] = w[tid];
  __syncthreads();
  int gid = blockIdx.x * 256 + tid;   // 401408
  int ow = gid % 28;
  int t1 = gid / 28;
  int oh = t1 % 28;
  int n = t1 / 28;
  bool h0 = oh > 0, h2 = oh < 27, w0 = ow > 0, w2 = ow < 27;
  const float* xb = x + (size_t)n * 32 * 784 + (oh - 1) * 28 + (ow - 1);
  float acc = bias[0];
  for (int ci = 0; ci < 32; ++ci) {
    const float* xc = xb + ci * 784;
    const float* wc = &ws_[ci * 9];
    if (h0 && w0) acc = fmaf(xc[0], wc[0], acc);
    if (h0)       acc = fmaf(xc[1], wc[1], acc);
    if (h0 && w2) acc = fmaf(xc[2], wc[2], acc);
    if (w0)       acc = fmaf(xc[28], wc[3], acc);
                  acc = fmaf(xc[29], wc[4], acc);
    if (w2)       acc = fmaf(xc[30], wc[5], acc);
    if (h2 && w0) acc = fmaf(xc[56], wc[6], acc);
    if (h2)       acc = fmaf(xc[57], wc[7], acc);
    if (h2 && w2) acc = fmaf(xc[58], wc[8], acc);
  }
  y[gid] = acc;
}

// ---------------- softplus row sums ----------------
__global__ void softplus_k(const float* __restrict__ L, float* __restrict__ sp) {
  __shared__ float red[256];
  int j = blockIdx.x, tid = threadIdx.x;
  float s = 0.f;
  for (int p = tid; p < 784; p += 256) {
    float v = L[j * 784 + p];
    s += fmaxf(v, 0.f) + log1pf(__expf(-fabsf(v)));
  }
  red[tid] = s;
  __syncthreads();
  for (int st = 128; st > 0; st >>= 1) {
    if (tid < st) red[tid] += red[tid + st];
    __syncthreads();
  }
  if (tid == 0) sp[j] = red[0];
}

// ---------------- cost GEMM (64x64 tile, 4x4/thread) ----------------
__global__ void cost_k(const float* __restrict__ X, const float* __restrict__ L,
                       const float* __restrict__ sp, float* __restrict__ Cm) {
  __shared__ float Xs[16][68], Ls[16][68];
  int tid = threadIdx.x;
  int tx = tid & 15, ty = tid >> 4;
  int i0 = blockIdx.y * 64, j0 = blockIdx.x * 64;
  int lrow = tid >> 2;
  int lk = (tid & 3) * 4;
  float acc[4][4] = {};
  for (int k0 = 0; k0 < 784; k0 += 16) {
    float4 xv = *(const float4*)&X[(size_t)(i0 + lrow) * 784 + k0 + lk];
    float4 lv = *(const float4*)&L[(size_t)(j0 + lrow) * 784 + k0 + lk];
    __syncthreads();
    Xs[lk + 0][lrow] = xv.x; Xs[lk + 1][lrow] = xv.y;
    Xs[lk + 2][lrow] = xv.z; Xs[lk + 3][lrow] = xv.w;
    Ls[lk + 0][lrow] = lv.x; Ls[lk + 1][lrow] = lv.y;
    Ls[lk + 2][lrow] = lv.z; Ls[lk + 3][lrow] = lv.w;
    __syncthreads();
#pragma unroll
    for (int k = 0; k < 16; ++k) {
      float4 a = *(const float4*)&Xs[k][ty * 4];
      float4 bq = *(const float4*)&Ls[k][tx * 4];
      acc[0][0] = fmaf(a.x, bq.x, acc[0][0]); acc[0][1] = fmaf(a.x, bq.y, acc[0][1]);
      acc[0][2] = fmaf(a.x, bq.z, acc[0][2]); acc[0][3] = fmaf(a.x, bq.w, acc[0][3]);
      acc[1][0] = fmaf(a.y, bq.x, acc[1][0]); acc[1][1] = fmaf(a.y, bq.y, acc[1][1]);
      acc[1][2] = fmaf(a.y, bq.z, acc[1][2]); acc[1][3] = fmaf(a.y, bq.w, acc[1][3]);
      acc[2][0] = fmaf(a.z, bq.x, acc[2][0]); acc[2][1] = fmaf(a.z, bq.y, acc[2][1]);
      acc[2][2] = fmaf(a.z, bq.z, acc[2][2]); acc[2][3] = fmaf(a.z, bq.w, acc[2][3]);
      acc[3][0] = fmaf(a.w, bq.x, acc[3][0]); acc[3][1] = fmaf(a.w, bq.y, acc[3][1]);
      acc[3][2] = fmaf(a.w, bq.z, acc[3][2]); acc[3][3] = fmaf(a.w, bq.w, acc[3][3]);
    }
  }
  float4 spv = *(const float4*)&sp[j0 + tx * 4];
#pragma unroll
  for (int r = 0; r < 4; ++r) {
    int irow = i0 + ty * 4 + r;
    float4 o;
    o.x = spv.x - acc[r][0];
    o.y = spv.y - acc[r][1];
    o.z = spv.z - acc[r][2];
    o.w = spv.w - acc[r][3];
    *(float4*)&Cm[(size_t)irow * 512 + j0 + tx * 4] = o;
  }
}

// ---------------- row max of (-C) ----------------
__global__ void rowmax_k(const float* __restrict__ C, float* __restrict__ M) {
  __shared__ float red[256];
  int i = blockIdx.x, tid = threadIdx.x;
  float m = -1e30f;
  for (int j = tid; j < 512; j += 256) m = fmaxf(m, -C[i * 512 + j]);
  red[tid] = m;
  __syncthreads();
  for (int st = 128; st > 0; st >>= 1) {
    if (tid < st) red[tid] = fmaxf(red[tid], red[tid + st]);
    __syncthreads();
  }
  if (tid == 0) M[i] = red[0];
}

// ---------------- SAG scan (1 wave, pipelined) ----------------
__global__ void sag_k(const float* __restrict__ C, const int* __restrict__ idx,
                      const float* __restrict__ Mrow, float* __restrict__ stored,
                      float* __restrict__ beta_out) {
  const int lane = threadIdx.x;   // 64
  const int jb = lane * 8;
  float beta[8], ssum[8], g[8], gp[8], gp2[8], st[8];
#pragma unroll
  for (int r = 0; r < 8; ++r) { beta[r] = 0.f; ssum[r] = 0.f; gp[r] = 0.f; gp2[r] = 0.f; }
  int ip = -1, ip2 = -1;
  const float invn = 1.0f / 512.0f, invn2 = invn * invn;
  float bmax = 0.0f;   // exact for t=0 (beta==0)

  int i_c = idx[0];
  int i_n = idx[1];
  float4 c0a = *(const float4*)&C[(size_t)i_c * 512 + jb];
  float4 c0b = *(const float4*)&C[(size_t)i_c * 512 + jb + 4];
  float4 c1a = *(const float4*)&C[(size_t)i_n * 512 + jb];
  float4 c1b = *(const float4*)&C[(size_t)i_n * 512 + jb + 4];
  {
    float4 sa = *(const float4*)&stored[(size_t)i_c * 512 + jb];
    float4 sb = *(const float4*)&stored[(size_t)i_c * 512 + jb + 4];
    st[0] = sa.x; st[1] = sa.y; st[2] = sa.z; st[3] = sa.w;
    st[4] = sb.x; st[5] = sb.y; st[6] = sb.z; st[7] = sb.w;
  }
  float Mi = Mrow[i_c];

  for (int t = 0; t < 1000; ++t) {
    const int i = i_c;
    const int i2 = (t + 2 < 1000) ? idx[t + 2] : idx[999];
    // prefetches (off the dependency chain)
    float4 c2a = *(const float4*)&C[(size_t)i2 * 512 + jb];
    float4 c2b = *(const float4*)&C[(size_t)i2 * 512 + jb + 4];
    float Mi1 = Mrow[i_n];
    float4 sna = *(const float4*)&stored[(size_t)i_n * 512 + jb];
    float4 snb = *(const float4*)&stored[(size_t)i_n * 512 + jb + 4];

    float cc[8] = {c0a.x, c0a.y, c0a.z, c0a.w, c0b.x, c0b.y, c0b.z, c0b.w};
    float mshift = Mi + bmax;
    float e[8];
    float S = 0.f;
#pragma unroll
    for (int r = 0; r < 8; ++r) {
      float s = beta[r] - cc[r];
      e[r] = __expf(s - mshift);
      S += e[r];
    }
    // lagged bmax for next iter: reduce CURRENT beta, interleaves with S-reduce
    float bm = beta[0];
#pragma unroll
    for (int r = 1; r < 8; ++r) bm = fmaxf(bm, beta[r]);
#pragma unroll
    for (int off = 32; off >= 1; off >>= 1) {
      S += __shfl_xor(S, off, 64);
      bm = fmaxf(bm, __shfl_xor(bm, off, 64));
    }
    if (S < 1e-30f) {   // exact fallback (wave-uniform, ~never taken)
      float m2 = -1e30f;
#pragma unroll
      for (int r = 0; r < 8; ++r) m2 = fmaxf(m2, beta[r] - cc[r]);
#pragma unroll
      for (int off = 32; off >= 1; off >>= 1) m2 = fmaxf(m2, __shfl_xor(m2, off, 64));
      S = 0.f;
#pragma unroll
      for (int r = 0; r < 8; ++r) { e[r] = __expf(beta[r] - cc[r] - m2); S += e[r]; }
#pragma unroll
      for (int off = 32; off >= 1; off >>= 1) S += __shfl_xor(S, off, 64);
    }
    float invS = 1.0f / S;
#pragma unroll
    for (int r = 0; r < 8; ++r) {
      g[r] = invn2 - invn * (e[r] * invS);
      ssum[r] += g[r] - st[r];
      beta[r] += ssum[r];   // lr/n_src = reg = 1
    }
    bmax = bm;
    // write stored row i
    float4 wa = make_float4(g[0], g[1], g[2], g[3]);
    float4 wb = make_float4(g[4], g[5], g[6], g[7]);
    *(float4*)&stored[(size_t)i * 512 + jb] = wa;
    *(float4*)&stored[(size_t)i * 512 + jb + 4] = wb;
    // rotate: stored row for t+1 with register bypass for recent writes
    float stn[8] = {sna.x, sna.y, sna.z, sna.w, snb.x, snb.y, snb.z, snb.w};
    if (i_n == i) {
#pragma unroll
      for (int r = 0; r < 8; ++r) stn[r] = g[r];
    } else if (i_n == ip) {
#pragma unroll
      for (int r = 0; r < 8; ++r) stn[r] = gp[r];
    } else if (i_n == ip2) {
#pragma unroll
      for (int r = 0; r < 8; ++r) stn[r] = gp2[r];
    }
#pragma unroll
    for (int r = 0; r < 8; ++r) { gp2[r] = gp[r]; gp[r] = g[r]; st[r] = stn[r]; }
    ip2 = ip; ip = i;
    c0a = c1a; c0b = c1b; c1a = c2a; c1b = c2b;
    Mi = Mi1;
    i_c = i_n; i_n = i2;
  }
#pragma unroll
  for (int r = 0; r < 8; ++r) beta_out[jb + r] = beta[r];
}

// ---------------- plan recovery + entropy rows ----------------
__global__ void p_k(const float* __restrict__ C, const float* __restrict__ beta,
                    float* __restrict__ P, float* __restrict__ rowsum) {
  __shared__ float red[256];
  int i = blockIdx.x, tid = threadIdx.x;
  float u0 = beta[tid] - C[(size_t)i * 512 + tid];
  float u1 = beta[tid + 256] - C[(size_t)i * 512 + tid + 256];
  float m = fmaxf(u0, u1);
  red[tid] = m;
  __syncthreads();
  for (int st = 128; st > 0; st >>= 1) {
    if (tid < st) red[tid] = fmaxf(red[tid], red[tid + st]);
    __syncthreads();
  }
  m = red[0];
  __syncthreads();
  float e0 = __expf(u0 - m), e1 = __expf(u1 - m);
  red[tid] = e0 + e1;
  __syncthreads();
  for (int st = 128; st > 0; st >>= 1) {
    if (tid < st) red[tid] += red[tid + st];
    __syncthreads();
  }
  float lse = m + logf(red[0]);
  __syncthreads();
  const float log512 = 6.238324625039508f;
  float p0 = __expf(u0 - lse) * (1.0f / 512.0f);
  float p1 = __expf(u1 - lse) * (1.0f / 512.0f);
  P[(size_t)i * 512 + tid] = p0;
  P[(size_t)i * 512 + tid + 256] = p1;
  float pl = p0 * (u0 - lse - log512) + p1 * (u1 - lse - log512);
  red[tid] = pl;
  __syncthreads();
  for (int st = 128; st > 0; st >>= 1) {
    if (tid < st) red[tid] += red[tid + st];
    __syncthreads();
  }
  if (tid == 0) rowsum[i] = red[0];
}

__global__ void kl_k(const float* __restrict__ rowsum, float* __restrict__ out_kl) {
  __shared__ float red[512];
  int tid = threadIdx.x;
  red[tid] = rowsum[tid];
  __syncthreads();
  for (int st = 256; st > 0; st >>= 1) {
    if (tid < st) red[tid] += red[tid + st];
    __syncthreads();
  }
  if (tid == 0) out_kl[0] = red[0] + 2.0f * 6.238324625039508f;
}

extern "C" void kernel_launch(void* const* d_in, const int* in_sizes, int n_in,
                              void* d_out, int out_size, void* d_ws, size_t ws_size,
                              hipStream_t stream) {
  const float* x = (const float*)d_in[0];
  const float* z = (const float*)d_in[1];
  const float* fc_w = (const float*)d_in[2];
  const float* fc_b = (const float*)d_in[3];
  const float* ct0_w = (const float*)d_in[4];
  const float* ct0_b = (const float*)d_in[5];
  const float* ct1_w = (const float*)d_in[6];
  const float* ct1_b = (const float*)d_in[7];
  const float* fct_w = (const float*)d_in[8];
  const float* fct_b = (const float*)d_in[9];
  const float* conv_w = (const float*)d_in[10];
  const float* conv_b = (const float*)d_in[11];
  const int* idx = (const int*)d_in[12];

  float* out = (float*)d_out;
  float* Pout = out;               // 512*512
  float* Cout = out + 262144;      // 512*512
  float* klout = out + 524288;     // 1

  float* ws = (float*)d_ws;
  float* h0 = ws;                       // 512*2048
  float* h1 = h0 + 1048576;             // 512*64*49
  float* h2 = h1 + 1605632;             // 512*32*196
  float* h3 = h2 + 3211264;             // 512*32*784
  float* logit = h3 + 12845056;         // 512*784
  float* sp = logit + 401408;           // 512
  float* beta = sp + 512;               // 512
  float* stored = beta + 512;           // 512*512
  float* rowsum = stored + 262144;      // 512
  float* Mrow = rowsum + 512;           // 512

  hipMemsetAsync(stored, 0, 262144 * sizeof(float), stream);

  fc_relu_k<<<1024, 256, 0, stream>>>(z, fc_w, fc_b, h0);
  convt_quad_k<128, 64, 4, 7><<<dim3(32, 8), 256, 0, stream>>>(h0, ct0_w, ct0_b, h1);
  convt_quad_k<64, 32, 7, 14><<<dim3(98, 4), 256, 0, stream>>>(h1, ct1_w, ct1_b, h2);
  convt_quad_k<32, 32, 14, 28><<<dim3(392, 4), 256, 0, stream>>>(h2, fct_w, fct_b, h3);
  conv_final_k<<<1568, 256, 0, stream>>>(h3, conv_w, conv_b, logit);
  softplus_k<<<512, 256, 0, stream>>>(logit, sp);
  cost_k<<<dim3(8, 8), 256, 0, stream>>>(x, logit, sp, Cout);
  rowmax_k<<<512, 256, 0, stream>>>(Cout, Mrow);
  sag_k<<<1, 64, 0, stream>>>(Cout, idx, Mrow, stored, beta);
  p_k<<<512, 256, 0, stream>>>(Cout, beta, Pout, rowsum);
  kl_k<<<1, 512, 0, stream>>>(rowsum, klout);
}

// Round 3
// 665.431 us; speedup vs baseline: 4.0713x; 1.3638x over previous
//
#include <hip/hip_runtime.h>
#include <hip/hip_bf16.h>
#include <math.h>

// x: [512,1,28,28]  z: [512,64]
// fc: 64 -> 2048 ; reshape [512,128,4,4]
// convT0: 128->64, 4x4 -> 7x7   (s2,p1,op0)
// convT1: 64->32, 7x7 -> 14x14  (s2,p1,op1)
// convT2: 32->32, 14x14 -> 28x28(s2,p1,op1)
// conv:   32->1, 28x28 (k3,p1)  -> logits [512,784]
// C[i,j] = sp[j] - dot(X[i], L[j])   (512x512, K=784)
// SAG scan 1000 iters ; P[i,:] = softmax(beta - C[i,:]) / 512
// kl = sum P log P + 2 log 512

typedef float vf4 __attribute__((ext_vector_type(4)));

// ---------------- FC ----------------
__global__ void fc_relu_k(const float* __restrict__ z, const float* __restrict__ w,
                          const float* __restrict__ b, float* __restrict__ out) {
  int n = blockIdx.x >> 1;
  int c0 = ((blockIdx.x & 1) << 10) + threadIdx.x * 4;
  const float* zr = z + n * 64;
  float4 acc = *(const float4*)&b[c0];
#pragma unroll
  for (int k = 0; k < 64; ++k) {
    float zk = zr[k];
    float4 wv = *(const float4*)&w[k * 2048 + c0];
    acc.x = fmaf(zk, wv.x, acc.x);
    acc.y = fmaf(zk, wv.y, acc.y);
    acc.z = fmaf(zk, wv.z, acc.z);
    acc.w = fmaf(zk, wv.w, acc.w);
  }
  acc.x = fmaxf(acc.x, 0.f); acc.y = fmaxf(acc.y, 0.f);
  acc.z = fmaxf(acc.z, 0.f); acc.w = fmaxf(acc.w, 0.f);
  *(float4*)&out[n * 2048 + c0] = acc;
}

// ---------------- ConvT (quad-gather) ----------------
#define TAPF(T, P, XV) { \
  const float4* w4_ = reinterpret_cast<const float4*>(&wt[((T) * CIN + ci) * 8]); \
  float4 wa_ = w4_[0], wb_ = w4_[1]; \
  acc[P][0] = fmaf(XV, wa_.x, acc[P][0]); \
  acc[P][1] = fmaf(XV, wa_.y, acc[P][1]); \
  acc[P][2] = fmaf(XV, wa_.z, acc[P][2]); \
  acc[P][3] = fmaf(XV, wa_.w, acc[P][3]); \
  acc[P][4] = fmaf(XV, wb_.x, acc[P][4]); \
  acc[P][5] = fmaf(XV, wb_.y, acc[P][5]); \
  acc[P][6] = fmaf(XV, wb_.z, acc[P][6]); \
  acc[P][7] = fmaf(XV, wb_.w, acc[P][7]); }

template <int CIN, int COUT, int HIN, int HOUT>
__global__ void convt_quad_k(const float* __restrict__ x, const float* __restrict__ w,
                             const float* __restrict__ bias, float* __restrict__ y) {
  constexpr bool FULL = (HOUT == 2 * HIN);
  constexpr int QP = HIN * HIN;
  __shared__ float wt[9 * CIN * 8];
  const int tid = threadIdx.x;
  const int g8 = blockIdx.y * 8;
  for (int e = tid; e < 9 * CIN * 8; e += 256) {
    int cl = e & 7;
    int rest = e >> 3;
    int ci = rest & (CIN - 1);
    int t = rest / CIN;
    wt[e] = w[((size_t)ci * COUT + g8 + cl) * 9 + t];
  }
  __syncthreads();

  int q = blockIdx.x * 256 + tid;
  int n = q / QP;
  int pq = q % QP;
  int a = pq / HIN, b = pq % HIN;
  const bool oka = (a + 1 < HIN), okb = (b + 1 < HIN);
  const float* xim = x + (size_t)n * CIN * QP + a * HIN + b;

  float acc[4][8];
#pragma unroll
  for (int p = 0; p < 4; ++p)
#pragma unroll
    for (int c = 0; c < 8; ++c) acc[p][c] = 0.f;

  for (int ci = 0; ci < CIN; ++ci) {
    const float* xc = xim + ci * QP;
    float x00 = xc[0];
    float x01 = okb ? xc[1] : 0.f;
    float x10 = oka ? xc[HIN] : 0.f;
    float x11 = (oka && okb) ? xc[HIN + 1] : 0.f;
    TAPF(4, 0, x00)
    TAPF(3, 1, x01) TAPF(5, 1, x00)
    TAPF(1, 2, x10) TAPF(7, 2, x00)
    TAPF(0, 3, x11) TAPF(2, 3, x10) TAPF(6, 3, x01) TAPF(8, 3, x00)
  }

  int oh0 = 2 * a, ow0 = 2 * b;
  bool vh = FULL || (oh0 + 1 < HOUT);
  bool vw = FULL || (ow0 + 1 < HOUT);
#pragma unroll
  for (int c = 0; c < 8; ++c) {
    float bv = bias[g8 + c];
    float o00 = fmaxf(acc[0][c] + bv, 0.f);
    float o01 = fmaxf(acc[1][c] + bv, 0.f);
    float o10 = fmaxf(acc[2][c] + bv, 0.f);
    float o11 = fmaxf(acc[3][c] + bv, 0.f);
    float* yb = y + (((size_t)n * COUT + g8 + c) * HOUT + oh0) * (size_t)HOUT + ow0;
    if (FULL) {
      *(float2*)yb = make_float2(o00, o01);
      *(float2*)(yb + HOUT) = make_float2(o10, o11);
    } else {
      yb[0] = o00;
      if (vw) yb[1] = o01;
      if (vh) yb[HOUT] = o10;
      if (vh && vw) yb[HOUT + 1] = o11;
    }
  }
}

// ---------------- final 32->1 conv ----------------
__global__ void conv_final_k(const float* __restrict__ x, const float* __restrict__ w,
                             const float* __restrict__ bias, float* __restrict__ y) {
  __shared__ float ws_[288];
  int tid = threadIdx.x;
  if (tid < 288) ws_[tid] = w[tid];
  __syncthreads();
  int gid = blockIdx.x * 256 + tid;
  int ow = gid % 28;
  int t1 = gid / 28;
  int oh = t1 % 28;
  int n = t1 / 28;
  bool h0 = oh > 0, h2 = oh < 27, w0 = ow > 0, w2 = ow < 27;
  const float* xb = x + (size_t)n * 32 * 784 + (oh - 1) * 28 + (ow - 1);
  float acc = bias[0];
  for (int ci = 0; ci < 32; ++ci) {
    const float* xc = xb + ci * 784;
    const float* wc = &ws_[ci * 9];
    if (h0 && w0) acc = fmaf(xc[0], wc[0], acc);
    if (h0)       acc = fmaf(xc[1], wc[1], acc);
    if (h0 && w2) acc = fmaf(xc[2], wc[2], acc);
    if (w0)       acc = fmaf(xc[28], wc[3], acc);
                  acc = fmaf(xc[29], wc[4], acc);
    if (w2)       acc = fmaf(xc[30], wc[5], acc);
    if (h2 && w0) acc = fmaf(xc[56], wc[6], acc);
    if (h2)       acc = fmaf(xc[57], wc[7], acc);
    if (h2 && w2) acc = fmaf(xc[58], wc[8], acc);
  }
  y[gid] = acc;
}

// ---------------- softplus row sums ----------------
__global__ void softplus_k(const float* __restrict__ L, float* __restrict__ sp) {
  __shared__ float red[256];
  int j = blockIdx.x, tid = threadIdx.x;
  float s = 0.f;
  for (int p = tid; p < 784; p += 256) {
    float v = L[j * 784 + p];
    s += fmaxf(v, 0.f) + log1pf(__expf(-fabsf(v)));
  }
  red[tid] = s;
  __syncthreads();
  for (int st = 128; st > 0; st >>= 1) {
    if (tid < st) red[tid] += red[tid + st];
    __syncthreads();
  }
  if (tid == 0) sp[j] = red[0];
}

// ---------------- cost GEMM (64x64 tile, 4x4/thread) ----------------
__global__ void cost_k(const float* __restrict__ X, const float* __restrict__ L,
                       const float* __restrict__ sp, float* __restrict__ Cm) {
  __shared__ float Xs[16][68], Ls[16][68];
  int tid = threadIdx.x;
  int tx = tid & 15, ty = tid >> 4;
  int i0 = blockIdx.y * 64, j0 = blockIdx.x * 64;
  int lrow = tid >> 2;
  int lk = (tid & 3) * 4;
  float acc[4][4] = {};
  for (int k0 = 0; k0 < 784; k0 += 16) {
    float4 xv = *(const float4*)&X[(size_t)(i0 + lrow) * 784 + k0 + lk];
    float4 lv = *(const float4*)&L[(size_t)(j0 + lrow) * 784 + k0 + lk];
    __syncthreads();
    Xs[lk + 0][lrow] = xv.x; Xs[lk + 1][lrow] = xv.y;
    Xs[lk + 2][lrow] = xv.z; Xs[lk + 3][lrow] = xv.w;
    Ls[lk + 0][lrow] = lv.x; Ls[lk + 1][lrow] = lv.y;
    Ls[lk + 2][lrow] = lv.z; Ls[lk + 3][lrow] = lv.w;
    __syncthreads();
#pragma unroll
    for (int k = 0; k < 16; ++k) {
      float4 a = *(const float4*)&Xs[k][ty * 4];
      float4 bq = *(const float4*)&Ls[k][tx * 4];
      acc[0][0] = fmaf(a.x, bq.x, acc[0][0]); acc[0][1] = fmaf(a.x, bq.y, acc[0][1]);
      acc[0][2] = fmaf(a.x, bq.z, acc[0][2]); acc[0][3] = fmaf(a.x, bq.w, acc[0][3]);
      acc[1][0] = fmaf(a.y, bq.x, acc[1][0]); acc[1][1] = fmaf(a.y, bq.y, acc[1][1]);
      acc[1][2] = fmaf(a.y, bq.z, acc[1][2]); acc[1][3] = fmaf(a.y, bq.w, acc[1][3]);
      acc[2][0] = fmaf(a.z, bq.x, acc[2][0]); acc[2][1] = fmaf(a.z, bq.y, acc[2][1]);
      acc[2][2] = fmaf(a.z, bq.z, acc[2][2]); acc[2][3] = fmaf(a.z, bq.w, acc[2][3]);
      acc[3][0] = fmaf(a.w, bq.x, acc[3][0]); acc[3][1] = fmaf(a.w, bq.y, acc[3][1]);
      acc[3][2] = fmaf(a.w, bq.z, acc[3][2]); acc[3][3] = fmaf(a.w, bq.w, acc[3][3]);
    }
  }
  float4 spv = *(const float4*)&sp[j0 + tx * 4];
#pragma unroll
  for (int r = 0; r < 4; ++r) {
    int irow = i0 + ty * 4 + r;
    float4 o;
    o.x = spv.x - acc[r][0];
    o.y = spv.y - acc[r][1];
    o.z = spv.z - acc[r][2];
    o.w = spv.w - acc[r][3];
    *(float4*)&Cm[(size_t)irow * 512 + j0 + tx * 4] = o;
  }
}

// ---------------- row max of (-C) ----------------
__global__ void rowmax_k(const float* __restrict__ C, float* __restrict__ M) {
  __shared__ float red[256];
  int i = blockIdx.x, tid = threadIdx.x;
  float m = -1e30f;
  for (int j = tid; j < 512; j += 256) m = fmaxf(m, -C[i * 512 + j]);
  red[tid] = m;
  __syncthreads();
  for (int st = 128; st > 0; st >>= 1) {
    if (tid < st) red[tid] = fmaxf(red[tid], red[tid + st]);
    __syncthreads();
  }
  if (tid == 0) M[i] = red[0];
}

// ---------------- cross-lane helpers (DPP + readlane) ----------------
template <int CTRL>
__device__ __forceinline__ float dpp_f(float x) {
  return __int_as_float(__builtin_amdgcn_update_dpp(0, __float_as_int(x), CTRL, 0xF, 0xF, true));
}
__device__ __forceinline__ float rdl(float v, int l) {
  return __int_as_float(__builtin_amdgcn_readlane(__float_as_int(v), l));
}
__device__ __forceinline__ float wsum16(float v) {
  v += dpp_f<0xB1>(v);    // xor1 (quad_perm [1,0,3,2])
  v += dpp_f<0x4E>(v);    // xor2 (quad_perm [2,3,0,1])
  v += dpp_f<0x141>(v);   // row_half_mirror (^7 -> other quad in 8)
  v += dpp_f<0x140>(v);   // row_mirror (^15 -> other 8 in 16)
  return (rdl(v, 0) + rdl(v, 16)) + (rdl(v, 32) + rdl(v, 48));
}
__device__ __forceinline__ float wmax64(float v) {
  v = fmaxf(v, dpp_f<0xB1>(v));
  v = fmaxf(v, dpp_f<0x4E>(v));
  v = fmaxf(v, dpp_f<0x141>(v));
  v = fmaxf(v, dpp_f<0x140>(v));
  return fmaxf(fmaxf(rdl(v, 0), rdl(v, 16)), fmaxf(rdl(v, 32), rdl(v, 48)));
}

// ---------------- SAG scan: 1 scan-wave + 7 L2-warm waves ----------------
#define LD_SLOT0(RN) { const float* bp_ = C + (size_t)(unsigned)(RN) * 512 + jb; \
  cc0L = *(const vf4*)bp_; cc0H = *(const vf4*)(bp_ + 4); \
  const float* sp_ = stored + (size_t)(unsigned)(RN) * 512 + jb; \
  st0L = *(const vf4*)sp_; st0H = *(const vf4*)(sp_ + 4); \
  M0 = Mrow[(RN)]; }
#define LD_SLOT1(RN) { const float* bp_ = C + (size_t)(unsigned)(RN) * 512 + jb; \
  cc1L = *(const vf4*)bp_; cc1H = *(const vf4*)(bp_ + 4); \
  const float* sp_ = stored + (size_t)(unsigned)(RN) * 512 + jb; \
  st1L = *(const vf4*)sp_; st1H = *(const vf4*)(sp_ + 4); \
  M1 = Mrow[(RN)]; }

#define SUB(R, RN, CCL, CCH, STL, STH, MM, LDM, H1R,H1GL,H1GH, H2R,H2GL,H2GH, H3R,H3GL,H3GH, H4R,H4GL,H4GH, H5R,H5GL,H5GH, GOL, GOH, DO_BM) \
{ \
  const int r_ = (R); \
  vf4 cL_ = CCL, cH_ = CCH, stL_ = STL, stH_ = STH; float Mu_ = MM; \
  LDM(RN); \
  if (r_ == (H5R)) { stL_ = H5GL; stH_ = H5GH; } \
  if (r_ == (H4R)) { stL_ = H4GL; stH_ = H4GH; } \
  if (r_ == (H3R)) { stL_ = H3GL; stH_ = H3GH; } \
  if (r_ == (H2R)) { stL_ = H2GL; stH_ = H2GH; } \
  if (r_ == (H1R)) { stL_ = H1GL; stH_ = H1GH; } \
  float shift_ = Mu_ + bm; \
  vf4 a0_ = betaL - (cL_ + shift_); \
  vf4 a1_ = betaH - (cH_ + shift_); \
  vf4 e0_, e1_; \
  e0_.x = __expf(a0_.x); e0_.y = __expf(a0_.y); e0_.z = __expf(a0_.z); e0_.w = __expf(a0_.w); \
  e1_.x = __expf(a1_.x); e1_.y = __expf(a1_.y); e1_.z = __expf(a1_.z); e1_.w = __expf(a1_.w); \
  vf4 es_ = e0_ + e1_; \
  float S_ = wsum16((es_.x + es_.z) + (es_.y + es_.w)); \
  if (!(S_ >= 1e-30f && S_ <= 1e30f)) { \
    float lm_ = fmaxf(fmaxf(fmaxf(a0_.x, a0_.y), fmaxf(a0_.z, a0_.w)), \
                      fmaxf(fmaxf(a1_.x, a1_.y), fmaxf(a1_.z, a1_.w))); \
    float m2_ = wmax64(lm_); \
    a0_ -= m2_; a1_ -= m2_; \
    e0_.x = __expf(a0_.x); e0_.y = __expf(a0_.y); e0_.z = __expf(a0_.z); e0_.w = __expf(a0_.w); \
    e1_.x = __expf(a1_.x); e1_.y = __expf(a1_.y); e1_.z = __expf(a1_.z); e1_.w = __expf(a1_.w); \
    es_ = e0_ + e1_; \
    S_ = wsum16((es_.x + es_.z) + (es_.y + es_.w)); \
  } \
  float kk_ = 0.001953125f * __builtin_amdgcn_rcpf(S_); \
  vf4 g0_ = 3.814697265625e-06f - e0_ * kk_; \
  vf4 g1_ = 3.814697265625e-06f - e1_ * kk_; \
  ssumL += g0_ - stL_; ssumH += g1_ - stH_; \
  betaL += ssumL; betaH += ssumH; \
  float* wp_ = stored + (size_t)(unsigned)r_ * 512 + jb; \
  *(vf4*)wp_ = g0_; *(vf4*)(wp_ + 4) = g1_; \
  GOL = g0_; GOH = g1_; \
  if (DO_BM) { \
    float bl_ = fmaxf(fmaxf(fmaxf(betaL.x, betaL.y), fmaxf(betaL.z, betaL.w)), \
                      fmaxf(fmaxf(betaH.x, betaH.y), fmaxf(betaH.z, betaH.w))); \
    bm_next = wmax64(bl_); \
  } \
}

__global__ void __launch_bounds__(512) sag_k(const float* __restrict__ C,
                                             const int* __restrict__ idx,
                                             const float* __restrict__ Mrow,
                                             float* __restrict__ stored,
                                             float* __restrict__ beta_out) {
  const int tid = threadIdx.x;
  if (tid >= 64) {
    // waves 1-7: pull C + stored + Mrow into this XCD's L2, concurrently with the scan
    const vf4* c4 = (const vf4*)C;
    const vf4* s4 = (const vf4*)stored;
    vf4 acc = {0.f, 0.f, 0.f, 0.f};
    for (int p = tid - 64; p < 65536; p += 448) { acc += c4[p]; acc += s4[p]; }
    float accs = acc.x + acc.y + acc.z + acc.w + Mrow[tid - 64];
    asm volatile("" :: "v"(accs));
    return;
  }

  const int lane = tid;
  const int jb = lane * 8;

  vf4 betaL = {0.f,0.f,0.f,0.f}, betaH = {0.f,0.f,0.f,0.f};
  vf4 ssumL = {0.f,0.f,0.f,0.f}, ssumH = {0.f,0.f,0.f,0.f};
  vf4 z4 = {0.f,0.f,0.f,0.f};
  vf4 pg0L=z4,pg0H=z4,pg1L=z4,pg1H=z4,pg2L=z4,pg2H=z4,pg3L=z4,pg3H=z4;
  vf4 o3gL=z4,o3gH=z4;
  vf4 g0L=z4,g0H=z4,g1L=z4,g1H=z4,g2L=z4,g2H=z4,g3L=z4,g3H=z4;
  int pr0=-1, pr1=-1, pr2=-1, pr3=-1, o3r=-1;
  float bm = 0.f, bm_next = 0.f;

  int4 iv0 = *(const int4*)&idx[0];
  int4 iv1 = *(const int4*)&idx[4];
  int itW0=iv0.x, itW1=iv0.y, itW2=iv0.z, itW3=iv0.w;
  int itW4=iv1.x, itW5=iv1.y, itW6=iv1.z, itW7=iv1.w;
  const int i999 = idx[999];

  vf4 cc0L, cc0H, st0L, st0H, cc1L, cc1H, st1L, st1H;
  float M0, M1;
  LD_SLOT0(itW0);
  LD_SLOT1(itW1);

  for (int t = 0; t < 1000; t += 4) {
    int n0, n1, n2, n3;
    if (t + 8 <= 996) {
      int4 nv = *(const int4*)&idx[t + 8];
      n0 = nv.x; n1 = nv.y; n2 = nv.z; n3 = nv.w;
    } else {
      n0 = n1 = n2 = n3 = i999;
    }

    SUB(itW0, itW2, cc0L, cc0H, st0L, st0H, M0, LD_SLOT0,
        pr3,pg3L,pg3H, pr2,pg2L,pg2H, pr1,pg1L,pg1H, pr0,pg0L,pg0H, o3r,o3gL,o3gH,
        g0L, g0H, 0)
    SUB(itW1, itW3, cc1L, cc1H, st1L, st1H, M1, LD_SLOT1,
        itW0,g0L,g0H, pr3,pg3L,pg3H, pr2,pg2L,pg2H, pr1,pg1L,pg1H, pr0,pg0L,pg0H,
        g1L, g1H, 0)
    SUB(itW2, itW4, cc0L, cc0H, st0L, st0H, M0, LD_SLOT0,
        itW1,g1L,g1H, itW0,g0L,g0H, pr3,pg3L,pg3H, pr2,pg2L,pg2H, pr1,pg1L,pg1H,
        g2L, g2H, 1)
    SUB(itW3, itW5, cc1L, cc1H, st1L, st1H, M1, LD_SLOT1,
        itW2,g2L,g2H, itW1,g1L,g1H, itW0,g0L,g0H, pr3,pg3L,pg3H, pr2,pg2L,pg2H,
        g3L, g3H, 0)

    // rotate history / windows
    o3r = pr3; o3gL = pg3L; o3gH = pg3H;
    pr0 = itW0; pg0L = g0L; pg0H = g0H;
    pr1 = itW1; pg1L = g1L; pg1H = g1H;
    pr2 = itW2; pg2L = g2L; pg2H = g2H;
    pr3 = itW3; pg3L = g3L; pg3H = g3H;
    itW0 = itW4; itW1 = itW5; itW2 = itW6; itW3 = itW7;
    itW4 = n0; itW5 = n1; itW6 = n2; itW7 = n3;
    bm = bm_next;
  }

  *(vf4*)(beta_out + jb) = betaL;
  *(vf4*)(beta_out + jb + 4) = betaH;
}

// ---------------- plan recovery + entropy rows ----------------
__global__ void p_k(const float* __restrict__ C, const float* __restrict__ beta,
                    float* __restrict__ P, float* __restrict__ rowsum) {
  __shared__ float red[256];
  int i = blockIdx.x, tid = threadIdx.x;
  float u0 = beta[tid] - C[(size_t)i * 512 + tid];
  float u1 = beta[tid + 256] - C[(size_t)i * 512 + tid + 256];
  float m = fmaxf(u0, u1);
  red[tid] = m;
  __syncthreads();
  for (int st = 128; st > 0; st >>= 1) {
    if (tid < st) red[tid] = fmaxf(red[tid], red[tid + st]);
    __syncthreads();
  }
  m = red[0];
  __syncthreads();
  float e0 = __expf(u0 - m), e1 = __expf(u1 - m);
  red[tid] = e0 + e1;
  __syncthreads();
  for (int st = 128; st > 0; st >>= 1) {
    if (tid < st) red[tid] += red[tid + st];
    __syncthreads();
  }
  float lse = m + logf(red[0]);
  __syncthreads();
  const float log512 = 6.238324625039508f;
  float p0 = __expf(u0 - lse) * (1.0f / 512.0f);
  float p1 = __expf(u1 - lse) * (1.0f / 512.0f);
  P[(size_t)i * 512 + tid] = p0;
  P[(size_t)i * 512 + tid + 256] = p1;
  float pl = p0 * (u0 - lse - log512) + p1 * (u1 - lse - log512);
  red[tid] = pl;
  __syncthreads();
  for (int st = 128; st > 0; st >>= 1) {
    if (tid < st) red[tid] += red[tid + st];
    __syncthreads();
  }
  if (tid == 0) rowsum[i] = red[0];
}

__global__ void kl_k(const float* __restrict__ rowsum, float* __restrict__ out_kl) {
  __shared__ float red[512];
  int tid = threadIdx.x;
  red[tid] = rowsum[tid];
  __syncthreads();
  for (int st = 256; st > 0; st >>= 1) {
    if (tid < st) red[tid] += red[tid + st];
    __syncthreads();
  }
  if (tid == 0) out_kl[0] = red[0] + 2.0f * 6.238324625039508f;
}

extern "C" void kernel_launch(void* const* d_in, const int* in_sizes, int n_in,
                              void* d_out, int out_size, void* d_ws, size_t ws_size,
                              hipStream_t stream) {
  const float* x = (const float*)d_in[0];
  const float* z = (const float*)d_in[1];
  const float* fc_w = (const float*)d_in[2];
  const float* fc_b = (const float*)d_in[3];
  const float* ct0_w = (const float*)d_in[4];
  const float* ct0_b = (const float*)d_in[5];
  const float* ct1_w = (const float*)d_in[6];
  const float* ct1_b = (const float*)d_in[7];
  const float* fct_w = (const float*)d_in[8];
  const float* fct_b = (const float*)d_in[9];
  const float* conv_w = (const float*)d_in[10];
  const float* conv_b = (const float*)d_in[11];
  const int* idx = (const int*)d_in[12];

  float* out = (float*)d_out;
  float* Pout = out;               // 512*512
  float* Cout = out + 262144;      // 512*512
  float* klout = out + 524288;     // 1

  float* ws = (float*)d_ws;
  float* h0 = ws;                       // 512*2048
  float* h1 = h0 + 1048576;             // 512*64*49
  float* h2 = h1 + 1605632;             // 512*32*196
  float* h3 = h2 + 3211264;             // 512*32*784
  float* logit = h3 + 12845056;         // 512*784
  float* sp = logit + 401408;           // 512
  float* beta = sp + 512;               // 512
  float* stored = beta + 512;           // 512*512
  float* rowsum = stored + 262144;      // 512
  float* Mrow = rowsum + 512;           // 512

  hipMemsetAsync(stored, 0, 262144 * sizeof(float), stream);

  fc_relu_k<<<1024, 256, 0, stream>>>(z, fc_w, fc_b, h0);
  convt_quad_k<128, 64, 4, 7><<<dim3(32, 8), 256, 0, stream>>>(h0, ct0_w, ct0_b, h1);
  convt_quad_k<64, 32, 7, 14><<<dim3(98, 4), 256, 0, stream>>>(h1, ct1_w, ct1_b, h2);
  convt_quad_k<32, 32, 14, 28><<<dim3(392, 4), 256, 0, stream>>>(h2, fct_w, fct_b, h3);
  conv_final_k<<<1568, 256, 0, stream>>>(h3, conv_w, conv_b, logit);
  softplus_k<<<512, 256, 0, stream>>>(logit, sp);
  cost_k<<<dim3(8, 8), 256, 0, stream>>>(x, logit, sp, Cout);
  rowmax_k<<<512, 256, 0, stream>>>(Cout, Mrow);
  sag_k<<<1, 512, 0, stream>>>(Cout, idx, Mrow, stored, beta);
  p_k<<<512, 256, 0, stream>>>(Cout, beta, Pout, rowsum);
  kl_k<<<1, 512, 0, stream>>>(rowsum, klout);
}

// Round 4
// 588.856 us; speedup vs baseline: 4.6008x; 1.1300x over previous
//
#include <hip/hip_runtime.h>
#include <hip/hip_bf16.h>
#include <math.h>

// x: [512,1,28,28]  z: [512,64]
// decoder: fc 64->2048 ; convT 128->64(4->7) ; 64->32(7->14) ; 32->32(14->28) ; conv 32->1
// Craw[i,j] = dot(X_i, L_j) ; C = sp_j - Craw ; sag 1000 iters ; P = softmax(beta - C)/512

typedef float vf4 __attribute__((ext_vector_type(4)));

// ---------------- FC ----------------
__global__ void fc_relu_k(const float* __restrict__ z, const float* __restrict__ w,
                          const float* __restrict__ b, float* __restrict__ out) {
  int n = blockIdx.x >> 1;
  int c0 = ((blockIdx.x & 1) << 10) + threadIdx.x * 4;
  const float* zr = z + n * 64;
  float4 acc = *(const float4*)&b[c0];
#pragma unroll
  for (int k = 0; k < 64; ++k) {
    float zk = zr[k];
    float4 wv = *(const float4*)&w[k * 2048 + c0];
    acc.x = fmaf(zk, wv.x, acc.x);
    acc.y = fmaf(zk, wv.y, acc.y);
    acc.z = fmaf(zk, wv.z, acc.z);
    acc.w = fmaf(zk, wv.w, acc.w);
  }
  acc.x = fmaxf(acc.x, 0.f); acc.y = fmaxf(acc.y, 0.f);
  acc.z = fmaxf(acc.z, 0.f); acc.w = fmaxf(acc.w, 0.f);
  *(float4*)&out[n * 2048 + c0] = acc;
}

// ---------------- ConvT (quad-gather) ----------------
#define TAPF(T, P, XV) { \
  const float4* w4_ = reinterpret_cast<const float4*>(&wt[((T) * CIN + ci) * 8]); \
  float4 wa_ = w4_[0], wb_ = w4_[1]; \
  acc[P][0] = fmaf(XV, wa_.x, acc[P][0]); \
  acc[P][1] = fmaf(XV, wa_.y, acc[P][1]); \
  acc[P][2] = fmaf(XV, wa_.z, acc[P][2]); \
  acc[P][3] = fmaf(XV, wa_.w, acc[P][3]); \
  acc[P][4] = fmaf(XV, wb_.x, acc[P][4]); \
  acc[P][5] = fmaf(XV, wb_.y, acc[P][5]); \
  acc[P][6] = fmaf(XV, wb_.z, acc[P][6]); \
  acc[P][7] = fmaf(XV, wb_.w, acc[P][7]); }

template <int CIN, int COUT, int HIN, int HOUT>
__global__ void convt_quad_k(const float* __restrict__ x, const float* __restrict__ w,
                             const float* __restrict__ bias, float* __restrict__ y) {
  constexpr bool FULL = (HOUT == 2 * HIN);
  constexpr int QP = HIN * HIN;
  __shared__ float wt[9 * CIN * 8];
  const int tid = threadIdx.x;
  const int g8 = blockIdx.y * 8;
  for (int e = tid; e < 9 * CIN * 8; e += 256) {
    int cl = e & 7;
    int rest = e >> 3;
    int ci = rest & (CIN - 1);
    int t = rest / CIN;
    wt[e] = w[((size_t)ci * COUT + g8 + cl) * 9 + t];
  }
  __syncthreads();

  int q = blockIdx.x * 256 + tid;
  int n = q / QP;
  int pq = q % QP;
  int a = pq / HIN, b = pq % HIN;
  const bool oka = (a + 1 < HIN), okb = (b + 1 < HIN);
  const float* xim = x + (size_t)n * CIN * QP + a * HIN + b;

  float acc[4][8];
#pragma unroll
  for (int p = 0; p < 4; ++p)
#pragma unroll
    for (int c = 0; c < 8; ++c) acc[p][c] = 0.f;

  for (int ci = 0; ci < CIN; ++ci) {
    const float* xc = xim + ci * QP;
    float x00 = xc[0];
    float x01 = okb ? xc[1] : 0.f;
    float x10 = oka ? xc[HIN] : 0.f;
    float x11 = (oka && okb) ? xc[HIN + 1] : 0.f;
    TAPF(4, 0, x00)
    TAPF(3, 1, x01) TAPF(5, 1, x00)
    TAPF(1, 2, x10) TAPF(7, 2, x00)
    TAPF(0, 3, x11) TAPF(2, 3, x10) TAPF(6, 3, x01) TAPF(8, 3, x00)
  }

  int oh0 = 2 * a, ow0 = 2 * b;
  bool vh = FULL || (oh0 + 1 < HOUT);
  bool vw = FULL || (ow0 + 1 < HOUT);
#pragma unroll
  for (int c = 0; c < 8; ++c) {
    float bv = bias[g8 + c];
    float o00 = fmaxf(acc[0][c] + bv, 0.f);
    float o01 = fmaxf(acc[1][c] + bv, 0.f);
    float o10 = fmaxf(acc[2][c] + bv, 0.f);
    float o11 = fmaxf(acc[3][c] + bv, 0.f);
    float* yb = y + (((size_t)n * COUT + g8 + c) * HOUT + oh0) * (size_t)HOUT + ow0;
    if (FULL) {
      *(float2*)yb = make_float2(o00, o01);
      *(float2*)(yb + HOUT) = make_float2(o10, o11);
    } else {
      yb[0] = o00;
      if (vw) yb[1] = o01;
      if (vh) yb[HOUT] = o10;
      if (vh && vw) yb[HOUT + 1] = o11;
    }
  }
}

// ---------------- final 32->1 conv ----------------
__global__ void conv_final_k(const float* __restrict__ x, const float* __restrict__ w,
                             const float* __restrict__ bias, float* __restrict__ y) {
  __shared__ float ws_[288];
  int tid = threadIdx.x;
  if (tid < 288) ws_[tid] = w[tid];
  __syncthreads();
  int gid = blockIdx.x * 256 + tid;
  int ow = gid % 28;
  int t1 = gid / 28;
  int oh = t1 % 28;
  int n = t1 / 28;
  bool h0 = oh > 0, h2 = oh < 27, w0 = ow > 0, w2 = ow < 27;
  const float* xb = x + (size_t)n * 32 * 784 + (oh - 1) * 28 + (ow - 1);
  float acc = bias[0];
  for (int ci = 0; ci < 32; ++ci) {
    const float* xc = xb + ci * 784;
    const float* wc = &ws_[ci * 9];
    if (h0 && w0) acc = fmaf(xc[0], wc[0], acc);
    if (h0)       acc = fmaf(xc[1], wc[1], acc);
    if (h0 && w2) acc = fmaf(xc[2], wc[2], acc);
    if (w0)       acc = fmaf(xc[28], wc[3], acc);
                  acc = fmaf(xc[29], wc[4], acc);
    if (w2)       acc = fmaf(xc[30], wc[5], acc);
    if (h2 && w0) acc = fmaf(xc[56], wc[6], acc);
    if (h2)       acc = fmaf(xc[57], wc[7], acc);
    if (h2 && w2) acc = fmaf(xc[58], wc[8], acc);
  }
  y[gid] = acc;
}

// ---------------- cross-lane helpers ----------------
template <int CTRL>
__device__ __forceinline__ float dpp_f(float x) {
  return __int_as_float(__builtin_amdgcn_update_dpp(0, __float_as_int(x), CTRL, 0xF, 0xF, true));
}
__device__ __forceinline__ float rdl(float v, int l) {
  return __int_as_float(__builtin_amdgcn_readlane(__float_as_int(v), l));
}
// total in lane63, returned via readlane (SGPR broadcast)
__device__ __forceinline__ float wsum64_l63(float v) {
  v += dpp_f<0xB1>(v);    // quad xor1
  v += dpp_f<0x4E>(v);    // quad xor2
  v += dpp_f<0x141>(v);   // row_half_mirror
  v += dpp_f<0x140>(v);   // row_mirror -> each 16-group has its sum
  v += dpp_f<0x142>(v);   // bcast15
  v += dpp_f<0x143>(v);   // bcast31  -> lane63 = total
  return rdl(v, 63);
}
__device__ __forceinline__ float wmax64_l63(float v) {
  v = fmaxf(v, dpp_f<0xB1>(v));
  v = fmaxf(v, dpp_f<0x4E>(v));
  v = fmaxf(v, dpp_f<0x141>(v));
  v = fmaxf(v, dpp_f<0x140>(v));
  v = fmaxf(v, dpp_f<0x142>(v));
  v = fmaxf(v, dpp_f<0x143>(v));
  return rdl(v, 63);
}

// ---------------- cost GEMM 32x64 + fused softplus row sums ----------------
__global__ void cost_k(const float* __restrict__ X, const float* __restrict__ L,
                       float* __restrict__ Craw, float* __restrict__ sp) {
  __shared__ float Xs[16][36];
  __shared__ float Ls[16][68];
  int tid = threadIdx.x;
  int i0 = blockIdx.y * 32, j0 = blockIdx.x * 64;
  int lrow = tid >> 2;          // 0..63
  int lq = tid & 3;             // col quad
  int xrow = tid & 31;
  int xq = (tid >> 5) & 3;
  bool doX = tid < 128;
  bool doSP = (blockIdx.y == 0);
  int tx = tid & 15, ty = tid >> 4;
  float acc[2][4] = {};
  float spacc = 0.f;
  for (int k0 = 0; k0 < 784; k0 += 16) {
    float4 lv = *(const float4*)&L[(size_t)(j0 + lrow) * 784 + k0 + lq * 4];
    float4 xv = {0.f, 0.f, 0.f, 0.f};
    if (doX) xv = *(const float4*)&X[(size_t)(i0 + xrow) * 784 + k0 + xq * 4];
    __syncthreads();
    Ls[lq * 4 + 0][lrow] = lv.x; Ls[lq * 4 + 1][lrow] = lv.y;
    Ls[lq * 4 + 2][lrow] = lv.z; Ls[lq * 4 + 3][lrow] = lv.w;
    if (doX) {
      Xs[xq * 4 + 0][xrow] = xv.x; Xs[xq * 4 + 1][xrow] = xv.y;
      Xs[xq * 4 + 2][xrow] = xv.z; Xs[xq * 4 + 3][xrow] = xv.w;
    }
    if (doSP) {
      spacc += fmaxf(lv.x, 0.f) + log1pf(__expf(-fabsf(lv.x)));
      spacc += fmaxf(lv.y, 0.f) + log1pf(__expf(-fabsf(lv.y)));
      spacc += fmaxf(lv.z, 0.f) + log1pf(__expf(-fabsf(lv.z)));
      spacc += fmaxf(lv.w, 0.f) + log1pf(__expf(-fabsf(lv.w)));
    }
    __syncthreads();
#pragma unroll
    for (int k = 0; k < 16; ++k) {
      float2 a = *(const float2*)&Xs[k][ty * 2];
      float4 bq = *(const float4*)&Ls[k][tx * 4];
      acc[0][0] = fmaf(a.x, bq.x, acc[0][0]); acc[0][1] = fmaf(a.x, bq.y, acc[0][1]);
      acc[0][2] = fmaf(a.x, bq.z, acc[0][2]); acc[0][3] = fmaf(a.x, bq.w, acc[0][3]);
      acc[1][0] = fmaf(a.y, bq.x, acc[1][0]); acc[1][1] = fmaf(a.y, bq.y, acc[1][1]);
      acc[1][2] = fmaf(a.y, bq.z, acc[1][2]); acc[1][3] = fmaf(a.y, bq.w, acc[1][3]);
    }
  }
#pragma unroll
  for (int r = 0; r < 2; ++r) {
    float4 o = make_float4(acc[r][0], acc[r][1], acc[r][2], acc[r][3]);
    *(float4*)&Craw[(size_t)(i0 + ty * 2 + r) * 512 + j0 + tx * 4] = o;
  }
  if (doSP) {
    float q = spacc;
    q += dpp_f<0xB1>(q);
    q += dpp_f<0x4E>(q);
    if (lq == 0) sp[j0 + lrow] = q;
  }
}

// ---------------- row max of (craw - sp) ----------------
__global__ void rowmax_k(const float* __restrict__ craw, const float* __restrict__ sp,
                         float* __restrict__ M) {
  __shared__ float red[256];
  int i = blockIdx.x, tid = threadIdx.x;
  float m = -1e30f;
  for (int j = tid; j < 512; j += 256) m = fmaxf(m, craw[(size_t)i * 512 + j] - sp[j]);
  red[tid] = m;
  __syncthreads();
  for (int st = 128; st > 0; st >>= 1) {
    if (tid < st) red[tid] = fmaxf(red[tid], red[tid + st]);
    __syncthreads();
  }
  if (tid == 0) M[i] = red[0];
}

// ---------------- SAG scan ----------------
#define SLD0(ROW) { unsigned ro_ = (unsigned)(ROW); \
  const float* cp_ = Craw + ((size_t)ro_ << 9) + jb; \
  s0cA = *(const vf4*)cp_; s0cB = *(const vf4*)(cp_ + 4); \
  const float* tp_ = stored + ((size_t)ro_ << 9) + jb; \
  s0sA = *(const vf4*)tp_; s0sB = *(const vf4*)(tp_ + 4); \
  s0M = Mrow[ro_]; }
#define SLD1(ROW) { unsigned ro_ = (unsigned)(ROW); \
  const float* cp_ = Craw + ((size_t)ro_ << 9) + jb; \
  s1cA = *(const vf4*)cp_; s1cB = *(const vf4*)(cp_ + 4); \
  const float* tp_ = stored + ((size_t)ro_ << 9) + jb; \
  s1sA = *(const vf4*)tp_; s1sB = *(const vf4*)(tp_ + 4); \
  s1M = Mrow[ro_]; }

#define STEP(IR, PFR, CA, CB, SA, SB, MU, LDM, \
             R1,A1,B1, R2,A2,B2, R3,A3,B3, R4,A4,B4, R5,A5,B5, R6,A6,B6, \
             GA, GB, DOBM) \
{ \
  vf4 c0_ = CA, c1_ = CB, t0_ = SA, t1_ = SB; float Mu_ = MU; \
  LDM(PFR); \
  const int r_ = (IR); \
  if (__builtin_expect((r_==(R1)) | (r_==(R2)) | (r_==(R3)) | \
                       (r_==(R4)) | (r_==(R5)) | (r_==(R6)), 0)) { \
    if (r_==(R6)) { t0_ = A6; t1_ = B6; } \
    if (r_==(R5)) { t0_ = A5; t1_ = B5; } \
    if (r_==(R4)) { t0_ = A4; t1_ = B4; } \
    if (r_==(R3)) { t0_ = A3; t1_ = B3; } \
    if (r_==(R2)) { t0_ = A2; t1_ = B2; } \
    if (r_==(R1)) { t0_ = A1; t1_ = B1; } \
  } \
  float sh_ = Mu_ + vbm; \
  vf4 cs0_ = (c0_ - spL) - sh_; \
  vf4 cs1_ = (c1_ - spH) - sh_; \
  vf4 u0_ = ssumL - t0_; \
  vf4 u1_ = ssumH - t1_; \
  vf4 a0_ = betaL + cs0_; \
  vf4 a1_ = betaH + cs1_; \
  vf4 e0_, e1_; \
  e0_.x = __expf(a0_.x); e0_.y = __expf(a0_.y); e0_.z = __expf(a0_.z); e0_.w = __expf(a0_.w); \
  e1_.x = __expf(a1_.x); e1_.y = __expf(a1_.y); e1_.z = __expf(a1_.z); e1_.w = __expf(a1_.w); \
  vf4 es_ = e0_ + e1_; \
  float S_ = wsum64_l63((es_.x + es_.z) + (es_.y + es_.w)); \
  S_ = fmaxf(S_, 1e-35f); \
  float kk_ = 0.001953125f * __builtin_amdgcn_rcpf(S_); \
  vf4 g0_ = 3.814697265625e-06f - e0_ * kk_; \
  vf4 g1_ = 3.814697265625e-06f - e1_ * kk_; \
  ssumL = u0_ + g0_; ssumH = u1_ + g1_; \
  betaL += ssumL; betaH += ssumH; \
  float* wp_ = stored + ((size_t)(unsigned)r_ << 9) + jb; \
  *(vf4*)wp_ = g0_; *(vf4*)(wp_ + 4) = g1_; \
  GA = g0_; GB = g1_; \
  if (DOBM) { \
    vf4 bm4_; \
    bm4_.x = fmaxf(betaL.x, betaH.x); bm4_.y = fmaxf(betaL.y, betaH.y); \
    bm4_.z = fmaxf(betaL.z, betaH.z); bm4_.w = fmaxf(betaL.w, betaH.w); \
    float bl_ = fmaxf(fmaxf(bm4_.x, bm4_.y), fmaxf(bm4_.z, bm4_.w)); \
    vbm = wmax64_l63(bl_); \
  } \
}

__global__ void __launch_bounds__(512, 1) sag_k(const float* __restrict__ Craw,
                                                const int* __restrict__ idx,
                                                const float* __restrict__ Mrow,
                                                const float* __restrict__ sp,
                                                float* __restrict__ stored,
                                                float* __restrict__ beta_out) {
  const int tid = threadIdx.x;
  if (tid >= 64) {
    // waves 1-7: warm C + stored into this XCD's L2 while wave 0 scans
    const vf4* c4 = (const vf4*)Craw;
    const vf4* s4 = (const vf4*)stored;
    vf4 acc = {0.f, 0.f, 0.f, 0.f};
    for (int p = tid - 64; p < 65536; p += 448) { acc += c4[p]; acc += s4[p]; }
    float accs = acc.x + acc.y + acc.z + acc.w + Mrow[tid - 64] + sp[tid - 64];
    asm volatile("" :: "v"(accs));
    return;
  }

  const int lane = tid;
  const int jb = lane * 8;
  const vf4 spL = *(const vf4*)(sp + jb);
  const vf4 spH = *(const vf4*)(sp + jb + 4);

  vf4 z4 = {0.f, 0.f, 0.f, 0.f};
  vf4 betaL = z4, betaH = z4, ssumL = z4, ssumH = z4;
  vf4 h1A = z4, h1B = z4, h2A = z4, h2B = z4, h3A = z4, h3B = z4;
  vf4 h4A = z4, h4B = z4, h5A = z4, h5B = z4, h6A = z4, h6B = z4;
  int hr1 = -1, hr2 = -1, hr3 = -1, hr4 = -1, hr5 = -1, hr6 = -1;
  float vbm = 0.f;

  int4 ia = *(const int4*)&idx[0];
  int4 ib = *(const int4*)&idx[4];
  int i0 = ia.x, i1 = ia.y, i2 = ia.z, i3 = ia.w;
  int i4 = ib.x, i5 = ib.y, i6 = ib.z, i7 = ib.w;

  vf4 s0cA, s0cB, s0sA, s0sB, s1cA, s1cB, s1sA, s1sB;
  float s0M, s1M;
  SLD0(i0);
  SLD1(i1);

  vf4 g0a, g0b, g1a, g1b, g2a, g2b, g3a, g3b;
  vf4 g4a, g4b, g5a, g5b, g6a, g6b, g7a, g7b;

  for (int t = 0; t < 1000; t += 8) {
    int tb = (t + 8 < 1000) ? (t + 8) : 992;
    int4 na = *(const int4*)&idx[tb];
    int4 nb = *(const int4*)&idx[tb + 4];

    STEP(i0, i2, s0cA, s0cB, s0sA, s0sB, s0M, SLD0,
         hr1,h1A,h1B, hr2,h2A,h2B, hr3,h3A,h3B, hr4,h4A,h4B, hr5,h5A,h5B, hr6,h6A,h6B,
         g0a, g0b, 0)
    STEP(i1, i3, s1cA, s1cB, s1sA, s1sB, s1M, SLD1,
         i0,g0a,g0b, hr1,h1A,h1B, hr2,h2A,h2B, hr3,h3A,h3B, hr4,h4A,h4B, hr5,h5A,h5B,
         g1a, g1b, 0)
    STEP(i2, i4, s0cA, s0cB, s0sA, s0sB, s0M, SLD0,
         i1,g1a,g1b, i0,g0a,g0b, hr1,h1A,h1B, hr2,h2A,h2B, hr3,h3A,h3B, hr4,h4A,h4B,
         g2a, g2b, 1)
    STEP(i3, i5, s1cA, s1cB, s1sA, s1sB, s1M, SLD1,
         i2,g2a,g2b, i1,g1a,g1b, i0,g0a,g0b, hr1,h1A,h1B, hr2,h2A,h2B, hr3,h3A,h3B,
         g3a, g3b, 0)
    STEP(i4, i6, s0cA, s0cB, s0sA, s0sB, s0M, SLD0,
         i3,g3a,g3b, i2,g2a,g2b, i1,g1a,g1b, i0,g0a,g0b, hr1,h1A,h1B, hr2,h2A,h2B,
         g4a, g4b, 0)
    STEP(i5, i7, s1cA, s1cB, s1sA, s1sB, s1M, SLD1,
         i4,g4a,g4b, i3,g3a,g3b, i2,g2a,g2b, i1,g1a,g1b, i0,g0a,g0b, hr1,h1A,h1B,
         g5a, g5b, 0)
    STEP(i6, na.x, s0cA, s0cB, s0sA, s0sB, s0M, SLD0,
         i5,g5a,g5b, i4,g4a,g4b, i3,g3a,g3b, i2,g2a,g2b, i1,g1a,g1b, i0,g0a,g0b,
         g6a, g6b, 1)
    STEP(i7, na.y, s1cA, s1cB, s1sA, s1sB, s1M, SLD1,
         i6,g6a,g6b, i5,g5a,g5b, i4,g4a,g4b, i3,g3a,g3b, i2,g2a,g2b, i1,g1a,g1b,
         g7a, g7b, 0)

    hr1 = i7; h1A = g7a; h1B = g7b;
    hr2 = i6; h2A = g6a; h2B = g6b;
    hr3 = i5; h3A = g5a; h3B = g5b;
    hr4 = i4; h4A = g4a; h4B = g4b;
    hr5 = i3; h5A = g3a; h5B = g3b;
    hr6 = i2; h6A = g2a; h6B = g2b;
    i0 = na.x; i1 = na.y; i2 = na.z; i3 = na.w;
    i4 = nb.x; i5 = nb.y; i6 = nb.z; i7 = nb.w;
  }

  *(vf4*)(beta_out + jb) = betaL;
  *(vf4*)(beta_out + jb + 4) = betaH;
}

// ---------------- plan recovery + C output + entropy rows ----------------
__global__ void p_k(const float* __restrict__ craw, const float* __restrict__ sp,
                    const float* __restrict__ beta, float* __restrict__ P,
                    float* __restrict__ Cout, float* __restrict__ rowsum) {
  __shared__ float red[256];
  int i = blockIdx.x, tid = threadIdx.x;
  float c0 = craw[(size_t)i * 512 + tid];
  float c1 = craw[(size_t)i * 512 + tid + 256];
  float sp0 = sp[tid], sp1 = sp[tid + 256];
  float u0 = (beta[tid] - sp0) + c0;
  float u1 = (beta[tid + 256] - sp1) + c1;
  Cout[(size_t)i * 512 + tid] = sp0 - c0;
  Cout[(size_t)i * 512 + tid + 256] = sp1 - c1;
  float m = fmaxf(u0, u1);
  red[tid] = m;
  __syncthreads();
  for (int st = 128; st > 0; st >>= 1) {
    if (tid < st) red[tid] = fmaxf(red[tid], red[tid + st]);
    __syncthreads();
  }
  m = red[0];
  __syncthreads();
  float e0 = __expf(u0 - m), e1 = __expf(u1 - m);
  red[tid] = e0 + e1;
  __syncthreads();
  for (int st = 128; st > 0; st >>= 1) {
    if (tid < st) red[tid] += red[tid + st];
    __syncthreads();
  }
  float lse = m + logf(red[0]);
  __syncthreads();
  const float log512 = 6.238324625039508f;
  float p0 = __expf(u0 - lse) * (1.0f / 512.0f);
  float p1 = __expf(u1 - lse) * (1.0f / 512.0f);
  P[(size_t)i * 512 + tid] = p0;
  P[(size_t)i * 512 + tid + 256] = p1;
  float pl = p0 * (u0 - lse - log512) + p1 * (u1 - lse - log512);
  red[tid] = pl;
  __syncthreads();
  for (int st = 128; st > 0; st >>= 1) {
    if (tid < st) red[tid] += red[tid + st];
    __syncthreads();
  }
  if (tid == 0) rowsum[i] = red[0];
}

__global__ void kl_k(const float* __restrict__ rowsum, float* __restrict__ out_kl) {
  __shared__ float red[512];
  int tid = threadIdx.x;
  red[tid] = rowsum[tid];
  __syncthreads();
  for (int st = 256; st > 0; st >>= 1) {
    if (tid < st) red[tid] += red[tid + st];
    __syncthreads();
  }
  if (tid == 0) out_kl[0] = red[0] + 2.0f * 6.238324625039508f;
}

extern "C" void kernel_launch(void* const* d_in, const int* in_sizes, int n_in,
                              void* d_out, int out_size, void* d_ws, size_t ws_size,
                              hipStream_t stream) {
  const float* x = (const float*)d_in[0];
  const float* z = (const float*)d_in[1];
  const float* fc_w = (const float*)d_in[2];
  const float* fc_b = (const float*)d_in[3];
  const float* ct0_w = (const float*)d_in[4];
  const float* ct0_b = (const float*)d_in[5];
  const float* ct1_w = (const float*)d_in[6];
  const float* ct1_b = (const float*)d_in[7];
  const float* fct_w = (const float*)d_in[8];
  const float* fct_b = (const float*)d_in[9];
  const float* conv_w = (const float*)d_in[10];
  const float* conv_b = (const float*)d_in[11];
  const int* idx = (const int*)d_in[12];

  float* out = (float*)d_out;
  float* Pout = out;               // 512*512
  float* Cout = out + 262144;      // 512*512
  float* klout = out + 524288;     // 1

  float* ws = (float*)d_ws;
  float* h0 = ws;                       // 512*2048  (dead after ct0 -> reused as Craw)
  float* h1 = h0 + 1048576;             // 512*64*49
  float* h2 = h1 + 1605632;             // 512*32*196
  float* h3 = h2 + 3211264;             // 512*32*784
  float* logit = h3 + 12845056;         // 512*784
  float* sp = logit + 401408;           // 512
  float* beta = sp + 512;               // 512
  float* stored = beta + 512;           // 512*512
  float* rowsum = stored + 262144;      // 512
  float* Mrow = rowsum + 512;           // 512
  float* Craw = h0;                     // aliases h0 (free after convt0)

  hipMemsetAsync(stored, 0, 262144 * sizeof(float), stream);

  fc_relu_k<<<1024, 256, 0, stream>>>(z, fc_w, fc_b, h0);
  convt_quad_k<128, 64, 4, 7><<<dim3(32, 8), 256, 0, stream>>>(h0, ct0_w, ct0_b, h1);
  convt_quad_k<64, 32, 7, 14><<<dim3(98, 4), 256, 0, stream>>>(h1, ct1_w, ct1_b, h2);
  convt_quad_k<32, 32, 14, 28><<<dim3(392, 4), 256, 0, stream>>>(h2, fct_w, fct_b, h3);
  conv_final_k<<<1568, 256, 0, stream>>>(h3, conv_w, conv_b, logit);
  cost_k<<<dim3(8, 16), 256, 0, stream>>>(x, logit, Craw, sp);
  rowmax_k<<<512, 256, 0, stream>>>(Craw, sp, Mrow);
  sag_k<<<1, 512, 0, stream>>>(Craw, idx, Mrow, sp, stored, beta);
  p_k<<<512, 256, 0, stream>>>(Craw, sp, beta, Pout, Cout, rowsum);
  kl_k<<<1, 512, 0, stream>>>(rowsum, klout);
}